// Round 2
// baseline (396.299 us; speedup 1.0000x reference)
//
#include <hip/hip_runtime.h>

#define NROW 8192
#define NCOL 8192
#define RANK 256

#define BM 128
#define BN 128

typedef __bf16  bf16x8 __attribute__((ext_vector_type(8)));
typedef float   f32x4  __attribute__((ext_vector_type(4)));

__device__ __forceinline__ unsigned short f2bf(float f) {
    // round-to-nearest-even fp32 -> bf16
    unsigned int u = __builtin_bit_cast(unsigned int, f);
    u += 0x7fffu + ((u >> 16) & 1u);
    return (unsigned short)(u >> 16);
}

// --- Prologue A: X (fp32, NROW x RANK) -> Xb (bf16) + x2 row norms ---
__global__ __launch_bounds__(256) void prep_x(const float* __restrict__ X,
                                              unsigned short* __restrict__ Xb,
                                              float* __restrict__ x2) {
    const int row  = blockIdx.x * 4 + (threadIdx.x >> 6);
    const int lane = threadIdx.x & 63;
    const float4 v = ((const float4*)(X + (size_t)row * RANK))[lane];
    float s = v.x * v.x + v.y * v.y + v.z * v.z + v.w * v.w;
    ushort4 b;
    b.x = f2bf(v.x); b.y = f2bf(v.y); b.z = f2bf(v.z); b.w = f2bf(v.w);
    ((ushort4*)(Xb + (size_t)row * RANK))[lane] = b;
    #pragma unroll
    for (int off = 32; off > 0; off >>= 1) s += __shfl_down(s, off);
    if (lane == 0) x2[row] = s;
}

// --- Prologue B: Y (fp32, RANK x NCOL) -> Ybt (bf16, NCOL x RANK) + y2 ---
__global__ __launch_bounds__(256) void prep_y(const float* __restrict__ Y,
                                              unsigned short* __restrict__ Ybt,
                                              float* __restrict__ y2) {
    __shared__ float tile[64][65];
    __shared__ float part[256];
    const int t  = threadIdx.x;
    const int j0 = blockIdx.x * 64;
    const int tq = t >> 6;
    const int tl = t & 63;
    float acc = 0.f;
    for (int c = 0; c < 4; ++c) {
        const int k0 = c * 64;
        #pragma unroll
        for (int i = 0; i < 16; ++i) {
            const int kk = tq * 16 + i;
            const float v = Y[(size_t)(k0 + kk) * NCOL + j0 + tl]; // coalesced
            tile[kk][tl] = v;
            acc += v * v;
        }
        __syncthreads();
        #pragma unroll
        for (int i = 0; i < 16; ++i) {
            const int jj = tq * 16 + i;
            Ybt[(size_t)(j0 + jj) * RANK + k0 + tl] = f2bf(tile[tl][jj]); // coalesced
        }
        __syncthreads();
    }
    part[t] = acc;
    __syncthreads();
    if (t < 64)
        y2[j0 + t] = part[t] + part[t + 64] + part[t + 128] + part[t + 192];
}

// --- Main: barrier-free MFMA GEMM, fragments loaded straight from cache ---
// K=256 is tiny and A/B are 8 MB bf16 total -> L2/LLC-resident. No LDS, no
// __syncthreads, fully-unrolled K so the scheduler pipelines loads freely.
__global__ __launch_bounds__(256, 3)
void l2_gemm(const unsigned short* __restrict__ A,   // Xb  [NROW][RANK]
             const unsigned short* __restrict__ Bt,  // Ybt [NCOL][RANK]
             const float* __restrict__ x2,
             const float* __restrict__ y2,
             const float* __restrict__ beta_p,
             float* __restrict__ out) {
    const int t    = threadIdx.x;
    const int wid  = t >> 6;
    const int lane = t & 63;

    // XCD-aware swizzle: 8-wide row-tile bands per XCD (bid%8 heuristic).
    // Each XCD keeps a 512 KB A-band hot in its 4 MB L2 while B streams.
    const int bid = blockIdx.x;
    const int xcd = bid & 7;
    const int loc = bid >> 3;             // 0..511
    const int tx  = xcd * 8 + (loc & 7);  // row tile 0..63
    const int ty  = loc >> 3;             // col tile 0..63

    const int rowBase = tx * BM + (wid >> 1) * 64;
    const int colBase = ty * BN + (wid & 1) * 64;

    const int frow = lane & 15;        // MFMA A/B row within 16
    const int fk   = (lane >> 4) * 8;  // 8-elem k chunk within 32

    const unsigned short* Ap = A  + (size_t)(rowBase + frow) * RANK + fk;
    const unsigned short* Bp = Bt + (size_t)(colBase + frow) * RANK + fk;

    f32x4 acc[4][4] = {};

    #pragma unroll
    for (int ks = 0; ks < RANK; ks += 32) {
        bf16x8 af[4], bfr[4];
        #pragma unroll
        for (int mt = 0; mt < 4; ++mt)
            af[mt] = *(const bf16x8*)(Ap + (size_t)(mt * 16) * RANK + ks);
        #pragma unroll
        for (int nt = 0; nt < 4; ++nt)
            bfr[nt] = *(const bf16x8*)(Bp + (size_t)(nt * 16) * RANK + ks);
        #pragma unroll
        for (int mt = 0; mt < 4; ++mt)
            #pragma unroll
            for (int nt = 0; nt < 4; ++nt)
                acc[mt][nt] = __builtin_amdgcn_mfma_f32_16x16x32_bf16(
                    af[mt], bfr[nt], acc[mt][nt], 0, 0, 0);
    }

    // fused epilogue: C/D layout col = lane&15, row = (lane>>4)*4 + reg
    const float beta = *beta_p;
    const int cRow0 = rowBase + (lane >> 4) * 4;
    const int cCol0 = colBase + (lane & 15);
    #pragma unroll
    for (int nt = 0; nt < 4; ++nt) {
        const int   col = cCol0 + nt * 16;
        const float yv  = y2[col];
        #pragma unroll
        for (int mt = 0; mt < 4; ++mt) {
            const float xv = x2[cRow0 + mt * 16];  // shared base, see loop below
            #pragma unroll
            for (int r = 0; r < 4; ++r) {
                const int row = cRow0 + mt * 16 + r;
                float d2 = x2[row] + yv - 2.0f * acc[mt][nt][r];
                d2 = d2 > 0.f ? d2 : 0.f;
                // non-temporal: don't let the 256 MB write stream evict the
                // L2-resident A/B working set
                __builtin_nontemporal_store(beta - sqrtf(d2),
                                            &out[(size_t)row * NCOL + col]);
            }
            (void)xv;
        }
    }
}

extern "C" void kernel_launch(void* const* d_in, const int* in_sizes, int n_in,
                              void* d_out, int out_size, void* d_ws, size_t ws_size,
                              hipStream_t stream) {
    const float* X    = (const float*)d_in[0];   // 8192 x 256
    const float* Y    = (const float*)d_in[1];   // 256 x 8192
    const float* beta = (const float*)d_in[2];   // scalar
    float* out = (float*)d_out;

    char* ws = (char*)d_ws;
    unsigned short* Xb  = (unsigned short*)(ws);                           // 4 MB
    unsigned short* Ybt = (unsigned short*)(ws + (size_t)4 * 1024 * 1024); // 4 MB
    float* x2 = (float*)(ws + (size_t)8 * 1024 * 1024);                    // 32 KB
    float* y2 = (float*)(ws + (size_t)8 * 1024 * 1024 + 32 * 1024);        // 32 KB

    prep_x<<<NROW / 4, 256, 0, stream>>>(X, Xb, x2);
    prep_y<<<NCOL / 64, 256, 0, stream>>>(Y, Ybt, y2);

    l2_gemm<<<(NROW / BM) * (NCOL / BN), 256, 0, stream>>>(Xb, Ybt, x2, y2, beta, out);
}